// Round 5
// baseline (1923.244 us; speedup 1.0000x reference)
//
#include <hip/hip_runtime.h>
#include <math.h>

#define NB 16
#define T  2048
#define D  512
#define BD 64
#define BT (NB*T)  // 32768

// workspace layout (float offsets)
#define OFF_K   0
#define OFF_V   (BT*BD)
#define OFF_Q   (2*BT*BD)
#define OFF_ETA (3*BT*BD)
#define OFF_H   (3*BT*BD + BT)
// total floats = 4*BT*BD + BT = 8,421,376  (~33.7 MB)

// gram scratch lives in d_out (64 MB; overwritten later by outproj):
// per 16-step chunk: KK[16*16] | KQ[16*16] | SC[16] | pad -> 544 floats
#define GSTRIDE 544
#define NCHUNK  (BT/16)   // 2048

// ---------------- DPP full-wave sum, result broadcast to all lanes ----------
__device__ __forceinline__ float wave_allsum(float x) {
  x += __int_as_float(__builtin_amdgcn_update_dpp(
      0, __float_as_int(x), 0x111, 0xf, 0xf, true));   // row_shr:1
  x += __int_as_float(__builtin_amdgcn_update_dpp(
      0, __float_as_int(x), 0x112, 0xf, 0xf, true));   // row_shr:2
  x += __int_as_float(__builtin_amdgcn_update_dpp(
      0, __float_as_int(x), 0x114, 0xf, 0xf, true));   // row_shr:4
  x += __int_as_float(__builtin_amdgcn_update_dpp(
      0, __float_as_int(x), 0x118, 0xf, 0xf, true));   // row_shr:8
  x += __int_as_float(__builtin_amdgcn_update_dpp(
      0, __float_as_int(x), 0x142, 0xa, 0xf, false));  // row_bcast:15 -> rows 1,3
  x += __int_as_float(__builtin_amdgcn_update_dpp(
      0, __float_as_int(x), 0x143, 0xc, 0xf, false));  // row_bcast:31 -> rows 2,3
  return __int_as_float(__builtin_amdgcn_readlane(__float_as_int(x), 63));
}

// DS-only barrier: waits lgkmcnt(0) (all loop lgkm ops are DS), leaves vmcnt
// in flight. Proven in r3/r4.
__device__ __forceinline__ void lds_barrier() {
  __builtin_amdgcn_sched_barrier(0);
  __builtin_amdgcn_s_waitcnt(0xC07F);  // vmcnt=63 (no wait), expcnt=7, lgkmcnt=0
  __builtin_amdgcn_s_barrier();
  __builtin_amdgcn_sched_barrier(0);
}

// ---------------- projection: K,V,Q = x @ W{k,v,q} + b ----------------
__device__ __forceinline__ void do_proj(const float* __restrict__ W,
                                        const float* __restrict__ bias,
                                        float* __restrict__ Out,
                                        const float* xs, int col, int rg,
                                        size_t row0) {
  float a0 = 0.f, a1 = 0.f, a2 = 0.f, a3 = 0.f;
  for (int d = 0; d < D; d += 4) {
    float w0 = W[(d + 0) * BD + col];
    float w1 = W[(d + 1) * BD + col];
    float w2 = W[(d + 2) * BD + col];
    float w3 = W[(d + 3) * BD + col];
    const float* xb = xs + (rg * 4) * D + d;
    float4 x0 = *(const float4*)(xb);
    float4 x1 = *(const float4*)(xb + D);
    float4 x2 = *(const float4*)(xb + 2 * D);
    float4 x3 = *(const float4*)(xb + 3 * D);
    a0 += x0.x * w0 + x0.y * w1 + x0.z * w2 + x0.w * w3;
    a1 += x1.x * w0 + x1.y * w1 + x1.z * w2 + x1.w * w3;
    a2 += x2.x * w0 + x2.y * w1 + x2.z * w2 + x2.w * w3;
    a3 += x3.x * w0 + x3.y * w1 + x3.z * w2 + x3.w * w3;
  }
  float bb = bias[col];
  Out[(row0 + rg * 4 + 0) * BD + col] = a0 + bb;
  Out[(row0 + rg * 4 + 1) * BD + col] = a1 + bb;
  Out[(row0 + rg * 4 + 2) * BD + col] = a2 + bb;
  Out[(row0 + rg * 4 + 3) * BD + col] = a3 + bb;
}

__global__ __launch_bounds__(256) void proj_kernel(
    const float* __restrict__ x,
    const float* __restrict__ Wk, const float* __restrict__ bk,
    const float* __restrict__ Wv, const float* __restrict__ bv,
    const float* __restrict__ Wq, const float* __restrict__ bq,
    float* __restrict__ Kout, float* __restrict__ Vout,
    float* __restrict__ Qout) {
  __shared__ __align__(16) float xs[16 * D];  // 32 KB
  const int tid = threadIdx.x;
  const size_t row0 = (size_t)blockIdx.x * 16;
  const float4* xg = (const float4*)(x + row0 * D);
  float4* xs4 = (float4*)xs;
#pragma unroll
  for (int i = 0; i < 8; i++) xs4[i * 256 + tid] = xg[i * 256 + tid];
  __syncthreads();
  const int col = tid & 63;
  const int rg = tid >> 6;  // 4 row-groups of 4 rows
  do_proj(Wk, bk, Kout, xs, col, rg, row0);
  do_proj(Wv, bv, Vout, xs, col, rg, row0);
  do_proj(Wq, bq, Qout, xs, col, rg, row0);
}

// ---------------- eta = sigmoid(x . lr_w + lr_b) ----------------
__global__ __launch_bounds__(256) void eta_kernel(const float* __restrict__ x,
                                                  const float* __restrict__ lr_w,
                                                  const float* __restrict__ lr_b,
                                                  float* __restrict__ eta) {
  const int tid = threadIdx.x;
  const int lane = tid & 63;
  const int wv = tid >> 6;
  const size_t r = (size_t)blockIdx.x * 4 + wv;  // one wave per row
  const float* xr = x + r * D + lane * 8;
  float4 a = *(const float4*)xr;
  float4 b = *(const float4*)(xr + 4);
  const float* lw = lr_w + lane * 8;
  float4 la = *(const float4*)lw;
  float4 lb = *(const float4*)(lw + 4);
  float p = a.x * la.x + a.y * la.y + a.z * la.z + a.w * la.w +
            b.x * lb.x + b.y * lb.y + b.z * lb.z + b.w * lb.w;
#pragma unroll
  for (int m = 32; m > 0; m >>= 1) p += __shfl_xor(p, m, 64);
  if (lane == 0) eta[r] = 1.0f / (1.0f + expf(-(p + lr_b[0])));
}

// ---------------- gram kernel: per 16-step chunk, precompute -------------
//   KK[i][t] = k_i . k_t ; KQ[i][t] = k_i . q_t ; SC[t] = sum g*(k+b-v)
__global__ __launch_bounds__(256) void gram_kernel(
    const float* __restrict__ K, const float* __restrict__ V,
    const float* __restrict__ Q, const float* __restrict__ ln_g,
    const float* __restrict__ ln_b, float* __restrict__ G) {
  __shared__ __align__(16) float sK[16][64], sQ[16][64], sV[16][64];
  __shared__ float sg[64], sb[64];
  const int tid = threadIdx.x;
  const size_t row0 = (size_t)blockIdx.x * 16;
  ((float4*)sK)[tid] = ((const float4*)(K + row0 * BD))[tid];
  ((float4*)sQ)[tid] = ((const float4*)(Q + row0 * BD))[tid];
  ((float4*)sV)[tid] = ((const float4*)(V + row0 * BD))[tid];
  if (tid < 64) { sg[tid] = ln_g[tid]; sb[tid] = ln_b[tid]; }
  __syncthreads();
  const int i = tid >> 4, t = tid & 15;
  float kk = 0.f, kq = 0.f;
#pragma unroll
  for (int d = 0; d < 64; d += 4) {
    float4 a4 = *(const float4*)&sK[i][d];
    float4 b4 = *(const float4*)&sK[t][d];
    float4 c4 = *(const float4*)&sQ[t][d];
    kk += a4.x * b4.x + a4.y * b4.y + a4.z * b4.z + a4.w * b4.w;
    kq += a4.x * c4.x + a4.y * c4.y + a4.z * c4.z + a4.w * c4.w;
  }
  size_t gb = (size_t)blockIdx.x * GSTRIDE;
  G[gb + i * 16 + t] = kk;
  G[gb + 256 + i * 16 + t] = kq;
  if (tid < 16) {
    float sc = 0.f;
    for (int d = 0; d < 64; d++)
      sc += sg[d] * (sK[tid][d] + sb[d] - sV[tid][d]);
    G[gb + 512 + tid] = sc;
  }
}

// ---------------- sequential TTT scan: chunked delta-rule, EIGHT waves ----
// Round 9: r4 measured 5.8 cyc/instr with 1 wave/SIMD -> per-wave issue
// cadence (~4cy) + stalls is the binding constraint. Fix: 8 waves/chain
// (2 per SIMD) so sibling waves fill cadence slots & stalls, plus cut the
// per-wave replicated instruction count:
//  * wave w owns W cols [8w,8w+8): matvec 16 FMA/step, W-update 10/step.
//  * partial combine: 2-level LDS tree (wave w reduces rows 2w,2w+1),
//    deterministic, ~4 instr/step; 3 barriers per 16-step chunk.
//  * p-corrections DEFERRED to the owning wave's end-of-chunk flush
//    (u2 = P0[t] + sum_{i<=t} coefs[i]*KQ[i,t]), static masked unroll.
//  * u-corrections (scatter, on the replicated path) and the 5 allsums +
//    scalar chain stay replicated -- the next lever if this round's
//    throughput model holds.
// Hazard ordering (single-buffered LDS, 3 barriers B1/B2/B3 per chunk n):
//  part2 writes(n) < B1 < reduce reads(n) < B2 ... B3 < part2 writes(n+1)
//  fin writes(n) < B2 < fin reads(n) < B1(n+1) < fin writes(n+1)
//  kls writes(n) < B1 < kls reads(phaseB n) < B3 < kls writes(n+1)
__global__ __launch_bounds__(512, 2)
void ttt_seq_kernel(
    const float* __restrict__ Kin, const float* __restrict__ Vin,
    const float* __restrict__ Qin, const float* __restrict__ eta_in,
    const float* __restrict__ W0, const float* __restrict__ ln_g,
    const float* __restrict__ ln_b, float* __restrict__ Hout,
    const float* __restrict__ gram) {
  __shared__ __align__(16) float2 part2[16][8][64];  // 64 KB wave partials
  __shared__ __align__(16) float2 fin[16][64];       // 8 KB combined u,p
  __shared__ __align__(16) float kls[16][64];        // 4 KB
  __shared__ __align__(16) float qls[16][64];        // 4 KB
  const int tid = threadIdx.x;
  const int lane = tid & 63;
  const int wvu = __builtin_amdgcn_readfirstlane(tid) >> 6;  // 0..7
  const int b = blockIdx.x;

  // W slice: w[j] = W0[lane*BD + 8*wvu + j], j = 0..7
  float w[8];
  {
    const float4* w04 = (const float4*)(W0 + (size_t)lane * BD + wvu * 8);
    float4 t0 = w04[0], t1 = w04[1];
    w[0] = t0.x; w[1] = t0.y; w[2] = t0.z; w[3] = t0.w;
    w[4] = t1.x; w[5] = t1.y; w[6] = t1.z; w[7] = t1.w;
  }
  const float g = ln_g[lane];
  const float bet = ln_b[lane];
  const float a = g * g;
  const float A2 = wave_allsum(a);

  size_t base = (size_t)b * T * BD;   // advances BD per step
  size_t ebase = (size_t)b * T;

  // per-lane rows of the current chunk (replicated across waves; reloaded
  // in-place for chunk+1 during phase B)
  float krow[16], qrow[16], vrow[16];
#pragma unroll
  for (int r = 0; r < 16; r++) {
    krow[r] = Kin[base + r * BD + lane];
    qrow[r] = Qin[base + r * BD + lane];
    vrow[r] = Vin[base + r * BD + lane];
  }
  float ev  = eta_in[ebase + lane];
  float evn = eta_in[ebase + 64 + lane];

  for (int c64 = 0; c64 < 32; c64++) {
    size_t eoff = (size_t)(c64 + 2) * 64;
    if (eoff >= T) eoff = 0;
    float ev2 = eta_in[ebase + eoff + lane];

    for (int cc = 0; cc < 4; cc++) {
      const int n = c64 * 4 + cc;
      // ---- gram loads (consumed in phase B / flush; phase A covers) ----
      const size_t gb = (size_t)(b * 128 + n) * GSTRIDE;
      float KKr[15];
#pragma unroll
      for (int t = 0; t < 15; t++) KKr[t] = gram[gb + t * 16 + lane];
      float SCv = gram[gb + 512 + lane];
      // owned-step KQ columns: lane i holds KQ[i][t_own]
      float KQcA = gram[gb + 256 + (size_t)lane * 16 + wvu];
      float KQcB = gram[gb + 256 + (size_t)lane * 16 + wvu + 8];

      // ---- stage rows (all waves write identical values; own in-order DS
      // makes own reads correct; cross-wave reads only after B1) ----
#pragma unroll
      for (int r = 0; r < 16; r++) {
        kls[r][lane] = krow[r];
        qls[r][lane] = qrow[r];
      }
      // ---- phase A: per-wave 8-col partial matvecs ----
#pragma unroll
      for (int r = 0; r < 16; r++) {
        const float4* kp = (const float4*)&kls[r][wvu * 8];
        const float4* qp = (const float4*)&qls[r][wvu * 8];
        float4 k0 = kp[0], k1 = kp[1], q0 = qp[0], q1 = qp[1];
        float ua = k0.x * w[0] + k0.y * w[1] + k0.z * w[2] + k0.w * w[3];
        float ub = k1.x * w[4] + k1.y * w[5] + k1.z * w[6] + k1.w * w[7];
        float pa = q0.x * w[0] + q0.y * w[1] + q0.z * w[2] + q0.w * w[3];
        float pb = q1.x * w[4] + q1.y * w[5] + q1.z * w[6] + q1.w * w[7];
        part2[r][wvu][lane] = make_float2(ua + ub, pa + pb);
      }

      lds_barrier();  // B1: partials + staged rows visible

      // ---- 2-level combine: wave w reduces rows 2w, 2w+1 ----
      {
        const int r0 = wvu * 2;
#pragma unroll
        for (int rr = 0; rr < 2; rr++) {
          const int r = r0 + rr;
          float2 s0 = part2[r][0][lane];
          float2 s1 = part2[r][1][lane];
          float2 s2 = part2[r][2][lane];
          float2 s3 = part2[r][3][lane];
          float2 s4 = part2[r][4][lane];
          float2 s5 = part2[r][5][lane];
          float2 s6 = part2[r][6][lane];
          float2 s7 = part2[r][7][lane];
          float su = ((s0.x + s1.x) + (s2.x + s3.x)) +
                     ((s4.x + s5.x) + (s6.x + s7.x));
          float sp = ((s0.y + s1.y) + (s2.y + s3.y)) +
                     ((s4.y + s5.y) + (s6.y + s7.y));
          fin[r][lane] = make_float2(su, sp);
        }
      }

      lds_barrier();  // B2: combined values visible

      float u0[16], p0[16];
#pragma unroll
      for (int r = 0; r < 16; r++) {
        float2 f2 = fin[r][lane];
        u0[r] = f2.x;
        p0[r] = f2.y;
      }

      float coefs[16];
      float p0sv0 = 0.f, p0sv1 = 0.f, qsv0 = 0.f, qsv1 = 0.f;

      // ---- phase B: 16 serial steps, no barriers ----
#pragma unroll
      for (int t = 0; t < 16; t++) {
        float u = u0[t];
        float kcur = krow[t], vcur = vrow[t], qcur = qrow[t];
        float ecur = __int_as_float(
            __builtin_amdgcn_readlane(__float_as_int(ev), cc * 16 + t));
        float c0 = g * (kcur + bet - vcur);

        float Su   = wave_allsum(u);
        float Suu  = wave_allsum(u * u);
        float Sau  = wave_allsum(a * u);
        float Sauu = wave_allsum(a * u * u);
        float Scu  = wave_allsum(c0 * u);
        float Sc   = __int_as_float(
            __builtin_amdgcn_readlane(__float_as_int(SCv), t));

        float mu = Su * (1.0f / 64);
        float var = Suu * (1.0f / 64) - mu * mu;
        float rstd = rsqrtf(var + 1e-6f);
        float xh = (u - mu) * rstd;
        float Axh   = rstd * (Sau - mu * A2);
        float Scxh  = rstd * (Scu - mu * Sc);
        float Saxh2 = rstd * rstd * (Sauu - 2.0f * mu * Sau + mu * mu * A2);
        float s1 = (2.0f / 64) * (Sc + Axh);
        float s2 = (2.0f / 64) * (Scxh + Saxh2);
        float dxh = (2.0f / 64) * (c0 + a * xh);
        float dldu = rstd * (dxh - s1 * (1.0f / 64) - xh * (s2 * (1.0f / 64)));
        float coef = -ecur * dldu;
        coefs[t] = coef;

        // critical correction first: u for step t+1
        if (t < 15)
          u0[t + 1] += coef * __int_as_float(
              __builtin_amdgcn_readlane(__float_as_int(KKr[t]), t + 1));
        // remaining u-scatter (off critical path)
#pragma unroll
        for (int s = t + 2; s < 16; s++)
          u0[s] += coef * __int_as_float(
              __builtin_amdgcn_readlane(__float_as_int(KKr[t]), s));

        // owner saves for deferred flush (static targets; uniform cond)
        if ((t & 7) == wvu) {
          if (t < 8) { p0sv0 = p0[t]; qsv0 = qcur; }
          else       { p0sv1 = p0[t]; qsv1 = qcur; }
        }

        // W-slice update (uniform LDS read of row t; next use = next chunk)
        {
          const float4* kp = (const float4*)&kls[t][wvu * 8];
          float4 k0 = kp[0], k1 = kp[1];
          w[0] += coef * k0.x; w[1] += coef * k0.y;
          w[2] += coef * k0.z; w[3] += coef * k0.w;
          w[4] += coef * k1.x; w[5] += coef * k1.y;
          w[6] += coef * k1.z; w[7] += coef * k1.w;
        }

        // reload row t for the NEXT chunk (16 steps of cover)
        krow[t] = Kin[base + 16 * BD + lane];
        qrow[t] = Qin[base + 16 * BD + lane];
        vrow[t] = Vin[base + 16 * BD + lane];
        base += BD;
      }

      // ---- deferred p-corrections + phase-2 LN for the 2 owned steps ----
      {
        float u2 = p0sv0;  // owned step t0 = wvu
#pragma unroll
        for (int i = 0; i < 8; i++) {
          float term = coefs[i] * __int_as_float(
              __builtin_amdgcn_readlane(__float_as_int(KQcA), i));
          u2 += (i <= wvu) ? term : 0.f;
        }
        float Su2  = wave_allsum(u2);
        float Suu2 = wave_allsum(u2 * u2);
        float mu2 = Su2 * (1.0f / 64);
        float rstd2 = rsqrtf(Suu2 * (1.0f / 64) - mu2 * mu2 + 1e-6f);
        Hout[base - (size_t)(16 - wvu) * BD + lane] =
            qsv0 + (u2 - mu2) * rstd2 * g + bet;
      }
      {
        float u2 = p0sv1;  // owned step t1 = wvu + 8
#pragma unroll
        for (int i = 0; i < 16; i++) {
          float term = coefs[i] * __int_as_float(
              __builtin_amdgcn_readlane(__float_as_int(KQcB), i));
          u2 += (i <= wvu + 8) ? term : 0.f;
        }
        float Su2  = wave_allsum(u2);
        float Suu2 = wave_allsum(u2 * u2);
        float mu2 = Su2 * (1.0f / 64);
        float rstd2 = rsqrtf(Suu2 * (1.0f / 64) - mu2 * mu2 + 1e-6f);
        Hout[base - (size_t)(8 - wvu) * BD + lane] =
            qsv1 + (u2 - mu2) * rstd2 * g + bet;
      }

      lds_barrier();  // B3: protect kls/qls/part2 against next chunk
    }
    ev = evn; evn = ev2;
  }
}

// ---------------- out projection: z = H @ Wo + bo ----------------
__global__ __launch_bounds__(256) void outproj_kernel(
    const float* __restrict__ H, const float* __restrict__ Wo,
    const float* __restrict__ bo, float* __restrict__ out) {
  __shared__ __align__(16) float ht[16 * BD];  // 4 KB
  const int tid = threadIdx.x;
  const size_t row0 = (size_t)blockIdx.x * 16;
  ((float4*)ht)[tid] = ((const float4*)(H + row0 * BD))[tid];
  __syncthreads();
  float acc0[16], acc1[16];
#pragma unroll
  for (int r = 0; r < 16; r++) { acc0[r] = 0.f; acc1[r] = 0.f; }
  for (int kk = 0; kk < BD; kk++) {
    float w0 = Wo[kk * D + tid];
    float w1 = Wo[kk * D + tid + 256];
#pragma unroll
    for (int r = 0; r < 16; r++) {
      float hv = ht[r * BD + kk];
      acc0[r] += hv * w0;
      acc1[r] += hv * w1;
    }
  }
  float b0 = bo[tid], b1 = bo[tid + 256];
#pragma unroll
  for (int r = 0; r < 16; r++) {
    out[(row0 + r) * D + tid] = acc0[r] + b0;
    out[(row0 + r) * D + tid + 256] = acc1[r] + b1;
  }
}

extern "C" void kernel_launch(void* const* d_in, const int* in_sizes, int n_in,
                              void* d_out, int out_size, void* d_ws,
                              size_t ws_size, hipStream_t stream) {
  (void)in_sizes; (void)n_in; (void)out_size; (void)ws_size;
  const float* x    = (const float*)d_in[0];
  const float* Wk   = (const float*)d_in[1];
  const float* bk   = (const float*)d_in[2];
  const float* Wv   = (const float*)d_in[3];
  const float* bv   = (const float*)d_in[4];
  const float* Wq   = (const float*)d_in[5];
  const float* bq   = (const float*)d_in[6];
  const float* Wo   = (const float*)d_in[7];
  const float* bo   = (const float*)d_in[8];
  const float* ln_g = (const float*)d_in[9];
  const float* ln_b = (const float*)d_in[10];
  const float* lr_w = (const float*)d_in[11];
  const float* lr_b = (const float*)d_in[12];
  const float* W0   = (const float*)d_in[13];

  float* ws  = (float*)d_ws;
  float* Kb  = ws + OFF_K;
  float* Vb  = ws + OFF_V;
  float* Qb  = ws + OFF_Q;
  float* ETA = ws + OFF_ETA;
  float* Hb  = ws + OFF_H;
  float* out = (float*)d_out;
  float* GRAM = out;  // scratch inside d_out; overwritten later by outproj

  proj_kernel<<<BT / 16, 256, 0, stream>>>(x, Wk, bk, Wv, bv, Wq, bq, Kb, Vb, Qb);
  eta_kernel<<<BT / 4, 256, 0, stream>>>(x, lr_w, lr_b, ETA);
  gram_kernel<<<NCHUNK, 256, 0, stream>>>(Kb, Vb, Qb, ln_g, ln_b, GRAM);
  ttt_seq_kernel<<<NB, 512, 0, stream>>>(Kb, Vb, Qb, ETA, W0, ln_g, ln_b, Hb, GRAM);
  outproj_kernel<<<BT / 16, 256, 0, stream>>>(Hb, Wo, bo, out);
}